// Round 5
// baseline (1723.018 us; speedup 1.0000x reference)
//
#include <hip/hip_runtime.h>

#define N_NODES  80000
#define N_EDGES  1280000
#define N_GRAPHS 512
#define DIM      64
#define NCLS     10

#define ETILE    2048
#define NTILE    625      // N_EDGES / ETILE exactly
#define NCB      625      // 128-node buckets; 80000/128 = 625 exactly
#define BSH      7        // log2(128)
#define BNODES   128
#define HPAD     640
#define AGPAD    68       // f32 row stride in LDS agg (bank spread)
#define SLOTS    8        // max graphs spanned by one bucket

typedef _Float16 half8f __attribute__((ext_vector_type(8)));  // 8 f16 (4 VGPRs)
typedef float float4f __attribute__((ext_vector_type(4)));    // 4 fp32 acc

static __device__ __forceinline__ unsigned short f2h(float f) {
    _Float16 h = (_Float16)f;                 // v_cvt_f16_f32, RNE
    return __builtin_bit_cast(unsigned short, h);
}
static __device__ __forceinline__ float h_lo(unsigned v) {
    return (float)__builtin_bit_cast(_Float16, (unsigned short)(v & 0xFFFF));
}
static __device__ __forceinline__ float h_hi(unsigned v) {
    return (float)__builtin_bit_cast(_Float16, (unsigned short)(v >> 16));
}

// ---------- Pass A (merged): blocks [0,NTILE) per-tile histogram over
// 128-node buckets; blocks [NTILE, NTILE+5000) cast x->f16; rest pack W1/W2.
__global__ __launch_bounds__(256) void k_histprep(const int* __restrict__ ei,
        const float* __restrict__ x,
        const float* __restrict__ wr1, const float* __restrict__ wo1,
        const float* __restrict__ wr2, const float* __restrict__ wo2,
        int* __restrict__ hmat, unsigned short* __restrict__ xb,
        unsigned short* __restrict__ wf) {
    __shared__ int hist[NCB];
    int bid = blockIdx.x, t = threadIdx.x;
    if (bid < NTILE) {
        int tile = bid;
        for (int i = t; i < NCB; i += 256) hist[i] = 0;
        __syncthreads();
        int base = tile * ETILE;
        int end = base + ETILE;
        for (int i = base + t; i < end; i += 256)
            atomicAdd(&hist[ei[N_EDGES + i] >> BSH], 1);
        __syncthreads();
        for (int i = t; i < NCB; i += 256) hmat[tile * HPAD + i] = hist[i];
        return;
    }
    int pb = bid - NTILE;
    if (pb < 5000) {
        int i = pb * 256 + t;                   // N_NODES*16 float4s
        float4 v = ((const float4*)x)[i];
        ushort4 o;
        o.x = f2h(v.x); o.y = f2h(v.y); o.z = f2h(v.z); o.w = f2h(v.w);
        ((ushort4*)xb)[i] = o;
    } else {
        int idx = (pb - 5000) * 256 + t;        // < 2*8192
        int j = idx & 7, lane = (idx >> 3) & 63;
        int ks = (idx >> 9) & 3, nt = (idx >> 11) & 3, l = idx >> 13;
        int k = ks * 32 + ((lane >> 4) & 3) * 8 + j;
        int n = nt * 16 + (lane & 15);
        const float* wr = (l == 0) ? wr1 : wr2;
        const float* wo = (l == 0) ? wo1 : wo2;
        float val = (k < 64) ? wr[n * 64 + k] : wo[n * 64 + (k - 64)];
        wf[idx] = f2h(val);
    }
}

// ---------- Pass B1: per-bucket exclusive scan across 625 tiles (3 elems/thr)
// Blocks 0..255 additionally zero the per-graph pool accumulators Se/Sn.
__global__ __launch_bounds__(256) void k_scanT(const int* __restrict__ hmat,
        int* __restrict__ obase, int* __restrict__ btot,
        float* __restrict__ Se, float* __restrict__ Sn) {
    __shared__ int sa[256], sb[256];
    int b = blockIdx.x, t = threadIdx.x;
    if (b < 256) {                       // zero 512*64 f32 in each pool array
        int idx = b * 256 + t;           // 65536 threads cover both arrays
        if (idx < N_GRAPHS * DIM) Se[idx] = 0.f;
        else                      Sn[idx - N_GRAPHS * DIM] = 0.f;
    }
    int j0 = 3 * t;
    int l0 = (j0     < NTILE) ? hmat[(j0    ) * HPAD + b] : 0;
    int l1 = (j0 + 1 < NTILE) ? hmat[(j0 + 1) * HPAD + b] : 0;
    int l2 = (j0 + 2 < NTILE) ? hmat[(j0 + 2) * HPAD + b] : 0;
    int s = l0 + l1 + l2;
    sa[t] = s; __syncthreads();
    int* sp = sa; int* dp = sb;
    for (int off = 1; off < 256; off <<= 1) {
        dp[t] = sp[t] + ((t >= off) ? sp[t - off] : 0);
        __syncthreads();
        int* tmp = sp; sp = dp; dp = tmp;
    }
    int ex = sp[t] - s;
    if (j0     < NTILE) obase[(j0    ) * HPAD + b] = ex;
    if (j0 + 1 < NTILE) obase[(j0 + 1) * HPAD + b] = ex + l0;
    if (j0 + 2 < NTILE) obase[(j0 + 2) * HPAD + b] = ex + l0 + l1;
    if (t == 255) btot[b] = sp[255];
}

// ---------- Pass B2: one-block scan of 625 bucket totals -> bucket bases
__global__ __launch_bounds__(256) void k_scanB(const int* __restrict__ btot,
        int* __restrict__ bucketbase) {
    __shared__ int sa[256], sb[256];
    int t = threadIdx.x;
    int b0 = t * 5;
    int v0 = (b0     < NCB) ? btot[b0]     : 0;
    int v1 = (b0 + 1 < NCB) ? btot[b0 + 1] : 0;
    int v2 = (b0 + 2 < NCB) ? btot[b0 + 2] : 0;
    int v3 = (b0 + 3 < NCB) ? btot[b0 + 3] : 0;
    int v4 = (b0 + 4 < NCB) ? btot[b0 + 4] : 0;
    int s = v0 + v1 + v2 + v3 + v4;
    sa[t] = s; __syncthreads();
    int* sp = sa; int* dp = sb;
    for (int off = 1; off < 256; off <<= 1) {
        dp[t] = sp[t] + ((t >= off) ? sp[t - off] : 0);
        __syncthreads();
        int* tmp = sp; sp = dp; dp = tmp;
    }
    int ex = sp[t] - s;
    if (b0     < NCB) bucketbase[b0]     = ex;
    if (b0 + 1 < NCB) bucketbase[b0 + 1] = ex + v0;
    if (b0 + 2 < NCB) bucketbase[b0 + 2] = ex + v0 + v1;
    if (b0 + 3 < NCB) bucketbase[b0 + 3] = ex + v0 + v1 + v2;
    if (b0 + 4 < NCB) bucketbase[b0 + 4] = ex + v0 + v1 + v2 + v3;
    if (t == 0) bucketbase[NCB] = N_EDGES;
}

// ---------- Pass C: scatter into bucket-sorted ebuf (src:17 | localdst:7)
__global__ __launch_bounds__(256) void k_scatter2(const int* __restrict__ ei,
        const int* __restrict__ obase, const int* __restrict__ bucketbase,
        int* __restrict__ ebuf) {
    __shared__ int cur[NCB];
    int tile = blockIdx.x, t = threadIdx.x;
    for (int i = t; i < NCB; i += 256)
        cur[i] = bucketbase[i] + obase[tile * HPAD + i];
    __syncthreads();
    int base = tile * ETILE;
    int end = base + ETILE;
    for (int i = base + t; i < end; i += 256) {
        int sv = ei[i], d = ei[N_EDGES + i];
        int p = atomicAdd(&cur[d >> BSH], 1);
        ebuf[p] = sv | ((d & 127) << 17);
    }
}

// ---------- fused gather + MFMA linear, edge-parallel over one bucket.
// Block = 128 nodes (8 waves). Phase 1: thread (edge-slot, 16B-chunk) loads
// X[src] chunk, accumulates into LDS f32 agg via ds_add_f32 (pad 68 -> banks
// spread by node, random dst -> ~2-way). No per-node loop, no shuffles, no
// tails, no node-level CSR. Phase 2: proven MFMA epilogue from LDS agg (f32).
__global__ __launch_bounds__(512) void k_gl(
        const unsigned short* __restrict__ Xin,
        const int* __restrict__ bucketbase, const int* __restrict__ ebuf,
        const unsigned short* __restrict__ wf, const float* __restrict__ bias,
        unsigned short* __restrict__ out, int relu) {
    __shared__ float agg[BNODES * AGPAD];
    int b = blockIdx.x, t = threadIdx.x;
    for (int i = t; i < BNODES * AGPAD; i += 512) agg[i] = 0.f;
    int s = bucketbase[b], e = bucketbase[b + 1];
    __syncthreads();
    const uint4* Xq = (const uint4*)Xin;
    int c = t & 7;                      // 16B chunk (dims c*8 .. c*8+7)
    int i = s + (t >> 3);               // edge slot, 64 slots per block
    for (; i + 64 < e; i += 128) {      // 2 row-loads in flight
        int pk0 = ebuf[i];
        int pk1 = ebuf[i + 64];
        uint4 v0 = Xq[(size_t)(pk0 & 0x1FFFF) * 8 + c];
        uint4 v1 = Xq[(size_t)(pk1 & 0x1FFFF) * 8 + c];
        float* a0 = agg + (pk0 >> 17) * AGPAD + c * 8;
        atomicAdd(a0 + 0, h_lo(v0.x)); atomicAdd(a0 + 1, h_hi(v0.x));
        atomicAdd(a0 + 2, h_lo(v0.y)); atomicAdd(a0 + 3, h_hi(v0.y));
        atomicAdd(a0 + 4, h_lo(v0.z)); atomicAdd(a0 + 5, h_hi(v0.z));
        atomicAdd(a0 + 6, h_lo(v0.w)); atomicAdd(a0 + 7, h_hi(v0.w));
        float* a1 = agg + (pk1 >> 17) * AGPAD + c * 8;
        atomicAdd(a1 + 0, h_lo(v1.x)); atomicAdd(a1 + 1, h_hi(v1.x));
        atomicAdd(a1 + 2, h_lo(v1.y)); atomicAdd(a1 + 3, h_hi(v1.y));
        atomicAdd(a1 + 4, h_lo(v1.z)); atomicAdd(a1 + 5, h_hi(v1.z));
        atomicAdd(a1 + 6, h_lo(v1.w)); atomicAdd(a1 + 7, h_hi(v1.w));
    }
    if (i < e) {
        int pk0 = ebuf[i];
        uint4 v0 = Xq[(size_t)(pk0 & 0x1FFFF) * 8 + c];
        float* a0 = agg + (pk0 >> 17) * AGPAD + c * 8;
        atomicAdd(a0 + 0, h_lo(v0.x)); atomicAdd(a0 + 1, h_hi(v0.x));
        atomicAdd(a0 + 2, h_lo(v0.y)); atomicAdd(a0 + 3, h_hi(v0.y));
        atomicAdd(a0 + 4, h_lo(v0.z)); atomicAdd(a0 + 5, h_hi(v0.z));
        atomicAdd(a0 + 6, h_lo(v0.w)); atomicAdd(a0 + 7, h_hi(v0.w));
    }
    __syncthreads();
    // phase 2: out = act([agg|x] @ W + b); 8 waves x 16 nodes
    int w = t >> 6, lane = t & 63;
    int quad = lane >> 4, l15 = lane & 15;
    int r = w * 16 + l15;               // bucket-local node row for A-frags
    int node = b * BNODES + r;
    const float* ar = agg + r * AGPAD;
    half8f a0f, a1f;
#pragma unroll
    for (int j = 0; j < 8; ++j) {
        a0f[j] = (_Float16)ar[quad * 8 + j];
        a1f[j] = (_Float16)ar[32 + quad * 8 + j];
    }
    const half8f* xr = (const half8f*)(Xin + (size_t)node * 64);
    half8f a2 = xr[quad];
    half8f a3 = xr[4 + quad];
    int orow = b * BNODES + w * 16 + quad * 4;
#pragma unroll
    for (int nt = 0; nt < 4; ++nt) {
        const half8f* wp = (const half8f*)(wf + ((size_t)(nt * 4) * 64 + lane) * 8);
        half8f b0 = wp[0];
        half8f b1 = wp[64];
        half8f b2 = wp[128];
        half8f b3 = wp[192];
        float4f acc = {0.f, 0.f, 0.f, 0.f};
        acc = __builtin_amdgcn_mfma_f32_16x16x32_f16(a0f, b0, acc, 0, 0, 0);
        acc = __builtin_amdgcn_mfma_f32_16x16x32_f16(a1f, b1, acc, 0, 0, 0);
        acc = __builtin_amdgcn_mfma_f32_16x16x32_f16(a2,  b2, acc, 0, 0, 0);
        acc = __builtin_amdgcn_mfma_f32_16x16x32_f16(a3,  b3, acc, 0, 0, 0);
        float bi = bias[nt * 16 + l15];
#pragma unroll
        for (int r2 = 0; r2 < 4; ++r2) {
            float v = acc[r2] + bi;
            if (relu) v = fmaxf(v, 0.f);
            out[(size_t)(orow + r2) * 64 + nt * 16 + l15] = f2h(v);
        }
    }
}

static __device__ __forceinline__ int lowerb(const int* a, int n, int key) {
    int lo = 0, hi = n;
    while (lo < hi) { int mid = (lo + hi) >> 1; if (a[mid] < key) lo = mid + 1; else hi = mid; }
    return lo;
}

// ---------- layer-3 + pool, stage 1: per-bucket edge/node sums into the
// few graphs this bucket spans (LDS f32, 8 octet-copies to avoid same-address
// serialization), flushed via global f32 atomicAdd into Se/Sn[512][64].
__global__ __launch_bounds__(256) void k_gsum2(const unsigned short* __restrict__ h2,
        const int* __restrict__ bucketbase, const int* __restrict__ ebuf,
        const int* __restrict__ batch,
        float* __restrict__ Se, float* __restrict__ Sn) {
    __shared__ float sge[SLOTS * 8 * AGPAD];
    __shared__ float sgn[SLOTS * 8 * AGPAD];
    __shared__ unsigned char gl[BNODES];
    int b = blockIdx.x, t = threadIdx.x;
    int gfirst = batch[b * BNODES];
    int glast  = batch[b * BNODES + BNODES - 1];
    int span = glast - gfirst + 1;
    for (int i = t; i < SLOTS * 8 * AGPAD; i += 256) { sge[i] = 0.f; sgn[i] = 0.f; }
    if (t < BNODES) gl[t] = (unsigned char)(batch[b * BNODES + t] - gfirst);
    __syncthreads();
    const uint4* Xq = (const uint4*)h2;
    int s = bucketbase[b], e = bucketbase[b + 1];
    int c = t & 7, oct = (t >> 3) & 7;
    if (span <= SLOTS) {
        int i = s + (t >> 3);                    // 32 edge slots
        for (; i + 32 < e; i += 64) {
            int pk0 = ebuf[i];
            int pk1 = ebuf[i + 32];
            uint4 v0 = Xq[(size_t)(pk0 & 0x1FFFF) * 8 + c];
            uint4 v1 = Xq[(size_t)(pk1 & 0x1FFFF) * 8 + c];
            float* a0 = sge + ((int)gl[pk0 >> 17] * 8 + oct) * AGPAD + c * 8;
            atomicAdd(a0 + 0, h_lo(v0.x)); atomicAdd(a0 + 1, h_hi(v0.x));
            atomicAdd(a0 + 2, h_lo(v0.y)); atomicAdd(a0 + 3, h_hi(v0.y));
            atomicAdd(a0 + 4, h_lo(v0.z)); atomicAdd(a0 + 5, h_hi(v0.z));
            atomicAdd(a0 + 6, h_lo(v0.w)); atomicAdd(a0 + 7, h_hi(v0.w));
            float* a1 = sge + ((int)gl[pk1 >> 17] * 8 + oct) * AGPAD + c * 8;
            atomicAdd(a1 + 0, h_lo(v1.x)); atomicAdd(a1 + 1, h_hi(v1.x));
            atomicAdd(a1 + 2, h_lo(v1.y)); atomicAdd(a1 + 3, h_hi(v1.y));
            atomicAdd(a1 + 4, h_lo(v1.z)); atomicAdd(a1 + 5, h_hi(v1.z));
            atomicAdd(a1 + 6, h_lo(v1.w)); atomicAdd(a1 + 7, h_hi(v1.w));
        }
        if (i < e) {
            int pk0 = ebuf[i];
            uint4 v0 = Xq[(size_t)(pk0 & 0x1FFFF) * 8 + c];
            float* a0 = sge + ((int)gl[pk0 >> 17] * 8 + oct) * AGPAD + c * 8;
            atomicAdd(a0 + 0, h_lo(v0.x)); atomicAdd(a0 + 1, h_hi(v0.x));
            atomicAdd(a0 + 2, h_lo(v0.y)); atomicAdd(a0 + 3, h_hi(v0.y));
            atomicAdd(a0 + 4, h_lo(v0.z)); atomicAdd(a0 + 5, h_hi(v0.z));
            atomicAdd(a0 + 6, h_lo(v0.w)); atomicAdd(a0 + 7, h_hi(v0.w));
        }
        for (int r = (t >> 3); r < BNODES; r += 32) {   // node (root) sums
            uint4 v = Xq[(size_t)(b * BNODES + r) * 8 + c];
            float* a0 = sgn + ((int)gl[r] * 8 + oct) * AGPAD + c * 8;
            atomicAdd(a0 + 0, h_lo(v.x)); atomicAdd(a0 + 1, h_hi(v.x));
            atomicAdd(a0 + 2, h_lo(v.y)); atomicAdd(a0 + 3, h_hi(v.y));
            atomicAdd(a0 + 4, h_lo(v.z)); atomicAdd(a0 + 5, h_hi(v.z));
            atomicAdd(a0 + 6, h_lo(v.w)); atomicAdd(a0 + 7, h_hi(v.w));
        }
        __syncthreads();
        for (int idx = t; idx < SLOTS * DIM; idx += 256) {
            int slot = idx >> 6, d = idx & 63;
            if (slot < span) {
                float ve = 0.f, vn = 0.f;
#pragma unroll
                for (int o = 0; o < 8; ++o) {
                    ve += sge[(slot * 8 + o) * AGPAD + d];
                    vn += sgn[(slot * 8 + o) * AGPAD + d];
                }
                atomicAdd(&Se[(size_t)(gfirst + slot) * DIM + d], ve);
                atomicAdd(&Sn[(size_t)(gfirst + slot) * DIM + d], vn);
            }
        }
    } else {  // pathological fallback: direct global atomics (never expected)
        for (int i = s + (t >> 3); i < e; i += 32) {
            int pk = ebuf[i];
            uint4 v = Xq[(size_t)(pk & 0x1FFFF) * 8 + c];
            int g = batch[b * BNODES + (pk >> 17)];
            float* a0 = Se + (size_t)g * DIM + c * 8;
            atomicAdd(a0 + 0, h_lo(v.x)); atomicAdd(a0 + 1, h_hi(v.x));
            atomicAdd(a0 + 2, h_lo(v.y)); atomicAdd(a0 + 3, h_hi(v.y));
            atomicAdd(a0 + 4, h_lo(v.z)); atomicAdd(a0 + 5, h_hi(v.z));
            atomicAdd(a0 + 6, h_lo(v.w)); atomicAdd(a0 + 7, h_hi(v.w));
        }
        for (int r = (t >> 3); r < BNODES; r += 32) {
            uint4 v = Xq[(size_t)(b * BNODES + r) * 8 + c];
            int g = batch[b * BNODES + r];
            float* a0 = Sn + (size_t)g * DIM + c * 8;
            atomicAdd(a0 + 0, h_lo(v.x)); atomicAdd(a0 + 1, h_hi(v.x));
            atomicAdd(a0 + 2, h_lo(v.y)); atomicAdd(a0 + 3, h_hi(v.y));
            atomicAdd(a0 + 4, h_lo(v.z)); atomicAdd(a0 + 5, h_hi(v.z));
            atomicAdd(a0 + 6, h_lo(v.w)); atomicAdd(a0 + 7, h_hi(v.w));
        }
    }
}

// ---------- stage 2: pooled = Se/cnt @ Wr3^T + b3 + Sn/cnt @ Wo3^T, head
__global__ __launch_bounds__(64) void k_head3(const float* __restrict__ Se,
        const float* __restrict__ Sn, const int* __restrict__ batch,
        const float* __restrict__ wr3, const float* __restrict__ wo3,
        const float* __restrict__ b3,
        const float* __restrict__ wlin, const float* __restrict__ blin,
        float* __restrict__ out) {
    __shared__ float s1[64], s2[64], pl[64];
    int g = blockIdx.x, t = threadIdx.x;
    int ns = lowerb(batch, N_NODES, g);
    int ne = lowerb(batch, N_NODES, g + 1);
    float inv = 1.f / (float)((ne > ns) ? (ne - ns) : 1);
    s1[t] = Se[(size_t)g * DIM + t] * inv;
    s2[t] = Sn[(size_t)g * DIM + t] * inv;
    __syncthreads();
    float acc = b3[t];
    for (int k = 0; k < 64; ++k)
        acc += s1[k] * wr3[t * 64 + k] + s2[k] * wo3[t * 64 + k];
    pl[t] = acc;
    __syncthreads();
    float myout = 0.f;
    for (int cls = 0; cls < NCLS; ++cls) {
        float vv = pl[t] * wlin[cls * 64 + t];
        for (int off = 32; off > 0; off >>= 1) vv += __shfl_xor(vv, off);
        if (t == cls) myout = vv + blin[cls];
    }
    if (t < NCLS) out[g * NCLS + t] = myout;
}

extern "C" void kernel_launch(void* const* d_in, const int* in_sizes, int n_in,
                              void* d_out, int out_size, void* d_ws, size_t ws_size,
                              hipStream_t stream) {
    const float* x     = (const float*)d_in[0];
    const int*   ei    = (const int*)d_in[1];
    const int*   batch = (const int*)d_in[2];
    const float* wr1 = (const float*)d_in[3];
    const float* b1  = (const float*)d_in[4];
    const float* wo1 = (const float*)d_in[5];
    const float* wr2 = (const float*)d_in[6];
    const float* b2  = (const float*)d_in[7];
    const float* wo2 = (const float*)d_in[8];
    const float* wr3 = (const float*)d_in[9];
    const float* b3  = (const float*)d_in[10];
    const float* wo3 = (const float*)d_in[11];
    const float* wlin = (const float*)d_in[12];
    const float* blin = (const float*)d_in[13];
    float* out = (float*)d_out;

    char* p = (char*)d_ws;
    auto alloc = [&](size_t bytes) { char* r = p; p += (bytes + 255) & ~(size_t)255; return r; };
    int*   hmat    = (int*)alloc((size_t)NTILE * HPAD * sizeof(int));
    int*   obase   = (int*)alloc((size_t)NTILE * HPAD * sizeof(int));
    int*   btot    = (int*)alloc(HPAD * sizeof(int));
    int*   bucketbase = (int*)alloc((NCB + 1) * sizeof(int));
    int*   ebuf    = (int*)alloc((size_t)N_EDGES * sizeof(int));
    unsigned short* wf  = (unsigned short*)alloc(2 * 8192 * sizeof(unsigned short));
    unsigned short* xbf = (unsigned short*)alloc((size_t)N_NODES * 64 * 2);
    unsigned short* hA  = (unsigned short*)alloc((size_t)N_NODES * 64 * 2);
    unsigned short* hB  = (unsigned short*)alloc((size_t)N_NODES * 64 * 2);
    float* Se      = (float*)alloc((size_t)N_GRAPHS * DIM * sizeof(float));
    float* Sn      = (float*)alloc((size_t)N_GRAPHS * DIM * sizeof(float));

    // CSR-lite build: bucket-sorted edge list only (no node-level CSR)
    k_histprep<<<NTILE + 5064, 256, 0, stream>>>(ei, x, wr1, wo1, wr2, wo2,
                                                 hmat, xbf, wf);
    k_scanT   <<<NCB,   256, 0, stream>>>(hmat, obase, btot, Se, Sn);
    k_scanB   <<<1,     256, 0, stream>>>(btot, bucketbase);
    k_scatter2<<<NTILE, 256, 0, stream>>>(ei, obase, bucketbase, ebuf);

    // layers 1+2: edge-parallel LDS-atomic gather + MFMA, one bucket/block
    k_gl<<<NCB, 512, 0, stream>>>(xbf, bucketbase, ebuf, wf,        b1, hA, 1);
    k_gl<<<NCB, 512, 0, stream>>>(hA,  bucketbase, ebuf, wf + 8192, b2, hB, 1);

    // layer 3 + pool
    k_gsum2<<<NCB, 256, 0, stream>>>(hB, bucketbase, ebuf, batch, Se, Sn);
    k_head3<<<N_GRAPHS, 64, 0, stream>>>(Se, Sn, batch, wr3, wo3, b3,
                                         wlin, blin, out);
}

// Round 7
// 366.581 us; speedup vs baseline: 4.7002x; 4.7002x over previous
//
#include <hip/hip_runtime.h>

#define N_NODES  80000
#define N_EDGES  1280000
#define N_GRAPHS 512
#define DIM      64
#define NCLS     10

#define ETILE    2048
#define NTILE    625      // N_EDGES / ETILE exactly
#define NCB      625      // 128-node buckets; 80000/128 = 625 exactly
#define BSH      7        // log2(128)
#define HPAD     640
#define NREG     4        // src regions of 20000 nodes (2.56MB f16 rows, L2-fit)

typedef _Float16 half8f __attribute__((ext_vector_type(8)));  // 8 f16 (4 VGPRs)
typedef float float4f __attribute__((ext_vector_type(4)));    // 4 fp32 acc

static __device__ __forceinline__ unsigned short f2h(float f) {
    _Float16 h = (_Float16)f;                 // v_cvt_f16_f32, RNE
    return __builtin_bit_cast(unsigned short, h);
}
static __device__ __forceinline__ float h_lo(unsigned v) {
    return (float)__builtin_bit_cast(_Float16, (unsigned short)(v & 0xFFFF));
}
static __device__ __forceinline__ float h_hi(unsigned v) {
    return (float)__builtin_bit_cast(_Float16, (unsigned short)(v >> 16));
}
// exact floor(s/20000) for s < 80000 (magic verified at region boundaries)
static __device__ __forceinline__ int srcreg(int s) {
    return (int)(((unsigned long long)(unsigned)s * 54975582ull) >> 40);
}

// ---------- Pass A (merged): blocks [0,NTILE) per-tile histogram over
// 128-node buckets; blocks [NTILE, NTILE+5000) cast x->f16; rest pack W1/W2.
__global__ __launch_bounds__(256) void k_histprep(const int* __restrict__ ei,
        const float* __restrict__ x,
        const float* __restrict__ wr1, const float* __restrict__ wo1,
        const float* __restrict__ wr2, const float* __restrict__ wo2,
        int* __restrict__ hmat, unsigned short* __restrict__ xb,
        unsigned short* __restrict__ wf) {
    __shared__ int hist[NCB];
    int bid = blockIdx.x, t = threadIdx.x;
    if (bid < NTILE) {
        int tile = bid;
        for (int i = t; i < NCB; i += 256) hist[i] = 0;
        __syncthreads();
        int base = tile * ETILE;
        int end = base + ETILE;
        for (int i = base + t; i < end; i += 256)
            atomicAdd(&hist[ei[N_EDGES + i] >> BSH], 1);
        __syncthreads();
        for (int i = t; i < NCB; i += 256) hmat[tile * HPAD + i] = hist[i];
        return;
    }
    int pb = bid - NTILE;
    if (pb < 5000) {
        int i = pb * 256 + t;                   // N_NODES*16 float4s
        float4 v = ((const float4*)x)[i];
        ushort4 o;
        o.x = f2h(v.x); o.y = f2h(v.y); o.z = f2h(v.z); o.w = f2h(v.w);
        ((ushort4*)xb)[i] = o;
    } else {
        int idx = (pb - 5000) * 256 + t;        // < 2*8192
        int j = idx & 7, lane = (idx >> 3) & 63;
        int ks = (idx >> 9) & 3, nt = (idx >> 11) & 3, l = idx >> 13;
        int k = ks * 32 + ((lane >> 4) & 3) * 8 + j;
        int n = nt * 16 + (lane & 15);
        const float* wr = (l == 0) ? wr1 : wr2;
        const float* wo = (l == 0) ? wo1 : wo2;
        float val = (k < 64) ? wr[n * 64 + k] : wo[n * 64 + (k - 64)];
        wf[idx] = f2h(val);
    }
}

// ---------- Pass B1: per-bucket exclusive scan across 625 tiles (3 elems/thr)
__global__ __launch_bounds__(256) void k_scanT(const int* __restrict__ hmat,
        int* __restrict__ obase, int* __restrict__ btot) {
    __shared__ int sa[256], sb[256];
    int b = blockIdx.x, t = threadIdx.x;
    int j0 = 3 * t;
    int l0 = (j0     < NTILE) ? hmat[(j0    ) * HPAD + b] : 0;
    int l1 = (j0 + 1 < NTILE) ? hmat[(j0 + 1) * HPAD + b] : 0;
    int l2 = (j0 + 2 < NTILE) ? hmat[(j0 + 2) * HPAD + b] : 0;
    int s = l0 + l1 + l2;
    sa[t] = s; __syncthreads();
    int* sp = sa; int* dp = sb;
    for (int off = 1; off < 256; off <<= 1) {
        dp[t] = sp[t] + ((t >= off) ? sp[t - off] : 0);
        __syncthreads();
        int* tmp = sp; sp = dp; dp = tmp;
    }
    int ex = sp[t] - s;
    if (j0     < NTILE) obase[(j0    ) * HPAD + b] = ex;
    if (j0 + 1 < NTILE) obase[(j0 + 1) * HPAD + b] = ex + l0;
    if (j0 + 2 < NTILE) obase[(j0 + 2) * HPAD + b] = ex + l0 + l1;
    if (t == 255) btot[b] = sp[255];
}

// ---------- Pass B2: one-block scan of 625 bucket totals -> bucket bases
__global__ __launch_bounds__(256) void k_scanB(const int* __restrict__ btot,
        int* __restrict__ bucketbase) {
    __shared__ int sa[256], sb[256];
    int t = threadIdx.x;
    int b0 = t * 5;
    int v0 = (b0     < NCB) ? btot[b0]     : 0;
    int v1 = (b0 + 1 < NCB) ? btot[b0 + 1] : 0;
    int v2 = (b0 + 2 < NCB) ? btot[b0 + 2] : 0;
    int v3 = (b0 + 3 < NCB) ? btot[b0 + 3] : 0;
    int v4 = (b0 + 4 < NCB) ? btot[b0 + 4] : 0;
    int s = v0 + v1 + v2 + v3 + v4;
    sa[t] = s; __syncthreads();
    int* sp = sa; int* dp = sb;
    for (int off = 1; off < 256; off <<= 1) {
        dp[t] = sp[t] + ((t >= off) ? sp[t - off] : 0);
        __syncthreads();
        int* tmp = sp; sp = dp; dp = tmp;
    }
    int ex = sp[t] - s;
    if (b0     < NCB) bucketbase[b0]     = ex;
    if (b0 + 1 < NCB) bucketbase[b0 + 1] = ex + v0;
    if (b0 + 2 < NCB) bucketbase[b0 + 2] = ex + v0 + v1;
    if (b0 + 3 < NCB) bucketbase[b0 + 3] = ex + v0 + v1 + v2;
    if (b0 + 4 < NCB) bucketbase[b0 + 4] = ex + v0 + v1 + v2 + v3;
    if (t == 0) bucketbase[NCB] = N_EDGES;
}

// ---------- Pass C: scatter into bucket-sorted ebuf (src:17 | localdst:7)
__global__ __launch_bounds__(256) void k_scatter2(const int* __restrict__ ei,
        const int* __restrict__ obase, const int* __restrict__ bucketbase,
        int* __restrict__ ebuf) {
    __shared__ int cur[NCB];
    int tile = blockIdx.x, t = threadIdx.x;
    for (int i = t; i < NCB; i += 256)
        cur[i] = bucketbase[i] + obase[tile * HPAD + i];
    __syncthreads();
    int base = tile * ETILE;
    int end = base + ETILE;
    for (int i = base + t; i < end; i += 256) {
        int sv = ei[i], d = ei[N_EDGES + i];
        int p = atomicAdd(&cur[d >> BSH], 1);
        ebuf[p] = sv | ((d & 127) << 17);
    }
}

// ---------- Pass D: per-bucket counting sort by (src-region, local node).
// Produces col (plain src) ordered (bucket, region, node) and
// rowptrR[b*512 + r*128 + n]; flat-contiguous, sentinel at NCB*512.
__global__ __launch_bounds__(256) void k_csr3(const int* __restrict__ ebuf,
        const int* __restrict__ bucketbase, int* __restrict__ rowptrR,
        int* __restrict__ col) {
    __shared__ int cnt[512], cur[512];
    __shared__ int sa[512], sb[512];
    int b = blockIdx.x, t = threadIdx.x;
    int s = bucketbase[b], e = bucketbase[b + 1];
    cnt[t] = 0; cnt[t + 256] = 0;
    __syncthreads();
    for (int i = s + t; i < e; i += 256) {
        int pk = ebuf[i];
        int key = srcreg(pk & 0x1FFFF) * 128 + (pk >> 17);
        atomicAdd(&cnt[key], 1);
    }
    __syncthreads();
    sa[t] = cnt[t]; sa[t + 256] = cnt[t + 256];
    __syncthreads();
    int* sp = sa; int* dp = sb;
    for (int off = 1; off < 512; off <<= 1) {
        int i1 = t + 256;
        int v0 = sp[t]  + ((t  >= off) ? sp[t  - off] : 0);
        int v1 = sp[i1] + ((i1 >= off) ? sp[i1 - off] : 0);
        __syncthreads();
        dp[t] = v0; dp[i1] = v1;
        __syncthreads();
        int* tmp = sp; sp = dp; dp = tmp;
    }
    int base0 = s + sp[t] - cnt[t];
    int base1 = s + sp[t + 256] - cnt[t + 256];
    cur[t] = base0; cur[t + 256] = base1;
    rowptrR[b * 512 + t]       = base0;
    rowptrR[b * 512 + 256 + t] = base1;
    if (b == 0 && t == 0) rowptrR[NCB * 512] = N_EDGES;
    __syncthreads();
    for (int i = s + t; i < e; i += 256) {
        int pk = ebuf[i];
        int src = pk & 0x1FFFF;
        int p = atomicAdd(&cur[srcreg(src) * 128 + (pk >> 17)], 1);
        col[p] = src;
    }
}

// ---------- fused gather + MFMA linear, region-phased.
// Block = 64 nodes, wave = 16 nodes. Region loop OUTER (all blocks sweep
// src regions 0..3 roughly in phase -> 2.56MB live src set, L2-resident);
// 16 per-node f16 accumulators persist in registers across regions
// (fully unrolled -> static indexing). Reduce + MFMA epilogue as before.
__global__ __launch_bounds__(256) void k_gatherlin(
        const unsigned short* __restrict__ Xin,
        const int* __restrict__ rowptrR, const int* __restrict__ col,
        const unsigned short* __restrict__ wf, const float* __restrict__ bias,
        unsigned short* __restrict__ out, int relu) {
    __shared__ uint4 sAgg[64][9];
    const half8f* Xq = (const half8f*)Xin;
    int t = threadIdx.x, w = t >> 6, lane = t & 63;
    int e = lane >> 3, c = lane & 7;
    int nb = blockIdx.x * 64 + w * 16;          // first node of this wave
    int rbase = (nb >> 7) * 512 + (nb & 127);   // flat rowptrR base (region 0)
    half8f accv[16] = {};
    for (int rg = 0; rg < NREG; ++rg) {
        int rp = (lane <= 16) ? rowptrR[rbase + rg * 128 + lane] : 0;
#pragma unroll
        for (int n = 0; n < 16; ++n) {
            int start = __shfl(rp, n), end = __shfl(rp, n + 1);
            int base = start;
            for (; base + 8 <= end; base += 8) {
                int i0 = col[base + e];
                accv[n] = accv[n] + Xq[(size_t)i0 * 8 + c];
            }
            if (base + e < end) {
                int i0 = col[base + e];
                accv[n] = accv[n] + Xq[(size_t)i0 * 8 + c];
            }
        }
    }
#pragma unroll
    for (int n = 0; n < 16; ++n) {
        half8f acc = accv[n];
#pragma unroll
        for (int off = 8; off < 64; off <<= 1) {
            uint4 au = __builtin_bit_cast(uint4, acc);
            uint4 bu;
            bu.x = __shfl_xor(au.x, off); bu.y = __shfl_xor(au.y, off);
            bu.z = __shfl_xor(au.z, off); bu.w = __shfl_xor(au.w, off);
            acc = acc + __builtin_bit_cast(half8f, bu);
        }
        if (e == 0) sAgg[w * 16 + n][c] = __builtin_bit_cast(uint4, acc);
    }
    // phase 2: out = act([agg|x] @ W + b)  (wave-private rows; lgkmcnt only)
    int quad = lane >> 4, l15 = lane & 15;
    int m = nb + l15;
    half8f a0 = *(const half8f*)&sAgg[w * 16 + l15][quad];
    half8f a1 = *(const half8f*)&sAgg[w * 16 + l15][4 + quad];
    const half8f* xr = (const half8f*)(Xin + (size_t)m * 64);
    half8f a2 = xr[quad];
    half8f a3 = xr[4 + quad];
    int orow = nb + quad * 4;
#pragma unroll
    for (int nt = 0; nt < 4; ++nt) {
        const half8f* wp = (const half8f*)(wf + ((size_t)(nt * 4) * 64 + lane) * 8);
        half8f b0 = wp[0];
        half8f b1 = wp[64];
        half8f b2 = wp[128];
        half8f b3 = wp[192];
        float4f acc = {0.f, 0.f, 0.f, 0.f};
        acc = __builtin_amdgcn_mfma_f32_16x16x32_f16(a0, b0, acc, 0, 0, 0);
        acc = __builtin_amdgcn_mfma_f32_16x16x32_f16(a1, b1, acc, 0, 0, 0);
        acc = __builtin_amdgcn_mfma_f32_16x16x32_f16(a2, b2, acc, 0, 0, 0);
        acc = __builtin_amdgcn_mfma_f32_16x16x32_f16(a3, b3, acc, 0, 0, 0);
        float bi = bias[nt * 16 + l15];
#pragma unroll
        for (int r2 = 0; r2 < 4; ++r2) {
            float v = acc[r2] + bi;
            if (relu) v = fmaxf(v, 0.f);
            out[(size_t)(orow + r2) * 64 + nt * 16 + l15] = f2h(v);
        }
    }
}

static __device__ __forceinline__ int lowerb(const int* a, int n, int key) {
    int lo = 0, hi = n;
    while (lo < hi) { int mid = (lo + hi) >> 1; if (a[mid] < key) lo = mid + 1; else hi = mid; }
    return lo;
}

// ---------- layer-3 collapse, stage 1: per-graph partial sums, 4 parts/graph.
// Edges of node range [a0,a1) are walked as <=8 contiguous (region, bucket)
// runs from rowptrR; region loop OUTER to stay in phase with other blocks.
__global__ __launch_bounds__(256) void k_gsum(const unsigned short* __restrict__ h2,
        const int* __restrict__ rowptrR, const int* __restrict__ col,
        const int* __restrict__ batch, float* __restrict__ S4) {
    __shared__ float red1[4][64];
    __shared__ float red2[4][64];
    const uint4* Xq = (const uint4*)h2;
    int g = blockIdx.x >> 2, part = blockIdx.x & 3;
    int t = threadIdx.x, w = t >> 6, lane = t & 63;
    int e = lane >> 3, c = lane & 7;
    int slot = w * 8 + e;                        // 32 edge slots
    int ns = lowerb(batch, N_NODES, g);
    int ne = lowerb(batch, N_NODES, g + 1);
    int a0 = ns + (int)(((long long)(ne - ns) * part) >> 2);
    int a1 = ns + (int)(((long long)(ne - ns) * (part + 1)) >> 2);
    float acc[8] = {0.f, 0.f, 0.f, 0.f, 0.f, 0.f, 0.f, 0.f};
    int b0 = a0 >> 7, b1 = (a1 - 1) >> 7;        // a0==a1 -> loop skipped
    for (int rg = 0; rg < NREG; ++rg) {
        for (int b = b0; b <= b1; ++b) {
            int nlo = a0 - (b << 7); if (nlo < 0) nlo = 0;
            int nhi = a1 - (b << 7); if (nhi > 128) nhi = 128;
            int rs = rowptrR[b * 512 + rg * 128 + nlo];
            int re = rowptrR[b * 512 + rg * 128 + nhi];
            for (int i = rs + slot; i < re; i += 32) {
                int src = col[i];
                uint4 v = Xq[(size_t)src * 8 + c];
                acc[0] += h_lo(v.x); acc[1] += h_hi(v.x);
                acc[2] += h_lo(v.y); acc[3] += h_hi(v.y);
                acc[4] += h_lo(v.z); acc[5] += h_hi(v.z);
                acc[6] += h_lo(v.w); acc[7] += h_hi(v.w);
            }
        }
    }
    float acc2[8] = {0.f, 0.f, 0.f, 0.f, 0.f, 0.f, 0.f, 0.f};
    for (int i = a0 + slot; i < a1; i += 32) {   // node (root) sums
        uint4 v = Xq[(size_t)i * 8 + c];
        acc2[0] += h_lo(v.x); acc2[1] += h_hi(v.x);
        acc2[2] += h_lo(v.y); acc2[3] += h_hi(v.y);
        acc2[4] += h_lo(v.z); acc2[5] += h_hi(v.z);
        acc2[6] += h_lo(v.w); acc2[7] += h_hi(v.w);
    }
#pragma unroll
    for (int off = 8; off < 64; off <<= 1) {
#pragma unroll
        for (int j = 0; j < 8; ++j) {
            acc[j]  += __shfl_xor(acc[j],  off);
            acc2[j] += __shfl_xor(acc2[j], off);
        }
    }
    if (e == 0) {
#pragma unroll
        for (int j = 0; j < 8; ++j) {
            red1[w][c * 8 + j] = acc[j];
            red2[w][c * 8 + j] = acc2[j];
        }
    }
    __syncthreads();
    if (t < 64) {
        S4[(size_t)blockIdx.x * 128 + t] =
            red1[0][t] + red1[1][t] + red1[2][t] + red1[3][t];
    } else if (t < 128) {
        int d = t - 64;
        S4[(size_t)blockIdx.x * 128 + 64 + d] =
            red2[0][d] + red2[1][d] + red2[2][d] + red2[3][d];
    }
}

// ---------- layer-3 collapse, stage 2: pooled matmuls + head (all fp32)
__global__ __launch_bounds__(64) void k_head2(const float* __restrict__ S4,
        const int* __restrict__ batch,
        const float* __restrict__ wr3, const float* __restrict__ wo3,
        const float* __restrict__ b3,
        const float* __restrict__ wlin, const float* __restrict__ blin,
        float* __restrict__ out) {
    __shared__ float s1[64], s2[64], pl[64];
    int g = blockIdx.x, t = threadIdx.x;
    int ns = lowerb(batch, N_NODES, g);
    int ne = lowerb(batch, N_NODES, g + 1);
    float inv = 1.f / (float)((ne > ns) ? (ne - ns) : 1);
    const float* Sg = S4 + (size_t)g * 4 * 128;
    s1[t] = (Sg[t]       + Sg[128 + t]       + Sg[256 + t]       + Sg[384 + t]) * inv;
    s2[t] = (Sg[64 + t]  + Sg[192 + t]       + Sg[320 + t]       + Sg[448 + t]) * inv;
    __syncthreads();
    float acc = b3[t];
    for (int k = 0; k < 64; ++k)
        acc += s1[k] * wr3[t * 64 + k] + s2[k] * wo3[t * 64 + k];
    pl[t] = acc;
    __syncthreads();
    float myout = 0.f;
    for (int cls = 0; cls < NCLS; ++cls) {
        float vv = pl[t] * wlin[cls * 64 + t];
        for (int off = 32; off > 0; off >>= 1) vv += __shfl_xor(vv, off);
        if (t == cls) myout = vv + blin[cls];
    }
    if (t < NCLS) out[g * NCLS + t] = myout;
}

extern "C" void kernel_launch(void* const* d_in, const int* in_sizes, int n_in,
                              void* d_out, int out_size, void* d_ws, size_t ws_size,
                              hipStream_t stream) {
    const float* x     = (const float*)d_in[0];
    const int*   ei    = (const int*)d_in[1];
    const int*   batch = (const int*)d_in[2];
    const float* wr1 = (const float*)d_in[3];
    const float* b1  = (const float*)d_in[4];
    const float* wo1 = (const float*)d_in[5];
    const float* wr2 = (const float*)d_in[6];
    const float* b2  = (const float*)d_in[7];
    const float* wo2 = (const float*)d_in[8];
    const float* wr3 = (const float*)d_in[9];
    const float* b3  = (const float*)d_in[10];
    const float* wo3 = (const float*)d_in[11];
    const float* wlin = (const float*)d_in[12];
    const float* blin = (const float*)d_in[13];
    float* out = (float*)d_out;

    char* p = (char*)d_ws;
    auto alloc = [&](size_t bytes) { char* r = p; p += (bytes + 255) & ~(size_t)255; return r; };
    int*   rowptrR = (int*)alloc(((size_t)NCB * 512 + 1) * sizeof(int));
    int*   hmat    = (int*)alloc((size_t)NTILE * HPAD * sizeof(int));
    int*   obase   = (int*)alloc((size_t)NTILE * HPAD * sizeof(int));
    int*   btot    = (int*)alloc(HPAD * sizeof(int));
    int*   bucketbase = (int*)alloc((NCB + 1) * sizeof(int));
    int*   ebuf    = (int*)alloc((size_t)N_EDGES * sizeof(int));
    int*   col     = (int*)alloc((size_t)N_EDGES * sizeof(int));
    unsigned short* wf  = (unsigned short*)alloc(2 * 8192 * sizeof(unsigned short));
    unsigned short* xbf = (unsigned short*)alloc((size_t)N_NODES * 64 * 2);
    unsigned short* hA  = (unsigned short*)alloc((size_t)N_NODES * 64 * 2);
    unsigned short* hB  = (unsigned short*)alloc((size_t)N_NODES * 64 * 2);
    float* S4      = (float*)alloc((size_t)N_GRAPHS * 4 * 128 * sizeof(float));

    // CSR build (two-level counting sort, region-aware leaf) + prep
    k_histprep<<<NTILE + 5064, 256, 0, stream>>>(ei, x, wr1, wo1, wr2, wo2,
                                                 hmat, xbf, wf);
    k_scanT   <<<NCB,   256, 0, stream>>>(hmat, obase, btot);
    k_scanB   <<<1,     256, 0, stream>>>(btot, bucketbase);
    k_scatter2<<<NTILE, 256, 0, stream>>>(ei, obase, bucketbase, ebuf);
    k_csr3    <<<NCB,   256, 0, stream>>>(ebuf, bucketbase, rowptrR, col);

    // layers 1+2: region-phased fused gather+linear
    k_gatherlin<<<N_NODES / 64, 256, 0, stream>>>(xbf, rowptrR, col, wf,        b1, hA, 1);
    k_gatherlin<<<N_NODES / 64, 256, 0, stream>>>(hA,  rowptrR, col, wf + 8192, b2, hB, 1);

    // layer 3 + pool collapsed
    k_gsum <<<N_GRAPHS * 4, 256, 0, stream>>>(hB, rowptrR, col, batch, S4);
    k_head2<<<N_GRAPHS,     64,  0, stream>>>(S4, batch, wr3, wo3, b3, wlin, blin, out);
}